// Round 7
// baseline (371.829 us; speedup 1.0000x reference)
//
#include <hip/hip_runtime.h>
#include <cstdint>
#include <cstddef>

#define B_SZ 16384
#define X_D  64
#define U_D  16
#define Z_D  32
#define H_D  1024
#define A_D  256
#define DT_C 0.02f

typedef _Float16 f16;
typedef f16   f16x8 __attribute__((ext_vector_type(8)));
typedef f16   f16x4 __attribute__((ext_vector_type(4)));
typedef float f32x4 __attribute__((ext_vector_type(4)));
typedef float f32x16 __attribute__((ext_vector_type(16)));

#define AS1 __attribute__((address_space(1)))
#define AS3 __attribute__((address_space(3)))

__device__ __forceinline__ void gld_lds16(const void* g, void* l) {
    __builtin_amdgcn_global_load_lds((AS1 void*)(g), (AS3 void*)(l), 16, 0, 0);
}

#define BARX()  do { asm volatile("" ::: "memory"); __builtin_amdgcn_s_barrier(); \
                     asm volatile("" ::: "memory"); } while (0)
#define LGK0()  do { asm volatile("s_waitcnt lgkmcnt(0)" ::: "memory"); \
                     __builtin_amdgcn_sched_barrier(0); } while (0)
#define WAITV6() asm volatile("s_waitcnt vmcnt(6)" ::: "memory")
#define WAITV0() asm volatile("s_waitcnt vmcnt(0)" ::: "memory")

struct GArg {
    const f16*  A;     // [M, lda] activations (row-major subview)
    const f16*  W;     // [N, K]   transposed weights, ld == K
    const float* bias; // [N]
    void*       C;     // output
    int lda, ldc, K;
};
// Up to 3 sub-GEMMs in one launch; yn0/yn1 = #N-tiles of sub-GEMM 0/1.
struct GSet { GArg g[3]; int yn0, yn1; };

// ---------------------------------------------------------------------------
// R0 kernel (verified best for small-K launches): 128x128x64 block,
// single 32KB stage buffer (5 blocks/CU), 32x32x16 MFMA. Used for L1/d1/d4.
// ---------------------------------------------------------------------------
template<int BM,int BN,int BK,int WM,int WN,bool SILU,int OM>
__launch_bounds__(256)
__global__ void gemm_k(GSet p)
{
    static_assert(OM != 1 || BN == 128, "OM1 repack assumes BN=128");
    int yb = blockIdx.y, gi = 0;
    if (yb >= p.yn0) { yb -= p.yn0; gi = 1; if (yb >= p.yn1) { yb -= p.yn1; gi = 2; } }
    const GArg ga = p.g[gi];

    constexpr int SEGROW = BK / 8;
    constexpr int SMASK  = (SEGROW < 8 ? SEGROW : 8) - 1;
    constexpr int WTM = BM / WM, WTN = BN / WN;
    static_assert(WTM % 32 == 0 && WTN % 32 == 0, "wave tile in 32x32 units");
    constexpr int RM = WTM / 32, RN = WTN / 32;
    constexpr int KS = BK / 16;
    constexpr int ITA = (BM * SEGROW) / 256;
    constexpr int ITB = (BN * SEGROW) / 256;

    constexpr int STAGE_B = (BM + BN) * BK * 2;
    constexpr int CS_B    = (OM == 1) ? BM * BN * 2 : 0;
    constexpr int SMEM_B  = STAGE_B > CS_B ? STAGE_B : CS_B;
    __shared__ __align__(16) char smem[SMEM_B];
    f16* As = (f16*)smem;
    f16* Bs = As + BM * BK;

    const int tid  = threadIdx.x;
    const int lane = tid & 63;
    const int wave = tid >> 6;
    const int wm = wave / WN, wn = wave % WN;
    const int l31 = lane & 31, half = lane >> 5;

    const size_t arow0 = (size_t)blockIdx.x * BM;
    const size_t brow0 = (size_t)yb * BN;
    const int lda = ga.lda, K = ga.K;

    const f16* aptr[ITA];
    const f16* bptr[ITB];
#pragma unroll
    for (int it = 0; it < ITA; ++it) {
        int s = it * 256 + tid;
        int row = s / SEGROW, st = s % SEGROW;
        int sg = st ^ (row & SMASK);
        aptr[it] = ga.A + (arow0 + row) * lda + sg * 8;
    }
#pragma unroll
    for (int it = 0; it < ITB; ++it) {
        int s = it * 256 + tid;
        int row = s / SEGROW, st = s % SEGROW;
        int sg = st ^ (row & SMASK);
        bptr[it] = ga.W + (brow0 + row) * K + sg * 8;
    }

    f32x16 acc[RM][RN];
#pragma unroll
    for (int i = 0; i < RM; ++i)
#pragma unroll
        for (int j = 0; j < RN; ++j)
#pragma unroll
            for (int r = 0; r < 16; ++r) acc[i][j][r] = 0.f;

    for (int k0 = 0; k0 < K; k0 += BK) {
#pragma unroll
        for (int it = 0; it < ITA; ++it) {
            gld_lds16(aptr[it], &As[(it * 256 + tid) * 8]);
            aptr[it] += BK;
        }
#pragma unroll
        for (int it = 0; it < ITB; ++it) {
            gld_lds16(bptr[it], &Bs[(it * 256 + tid) * 8]);
            bptr[it] += BK;
        }
        __syncthreads();

#pragma unroll
        for (int ks = 0; ks < KS; ++ks) {
            f16x8 af[RM], bf[RN];
#pragma unroll
            for (int i = 0; i < RM; ++i) {
                int row = wm * WTM + i * 32 + l31;
                int st  = (ks * 2 + half) ^ (row & SMASK);
                af[i] = *(const f16x8*)&As[(row * SEGROW + st) * 8];
            }
#pragma unroll
            for (int j = 0; j < RN; ++j) {
                int row = wn * WTN + j * 32 + l31;
                int st  = (ks * 2 + half) ^ (row & SMASK);
                bf[j] = *(const f16x8*)&Bs[(row * SEGROW + st) * 8];
            }
#pragma unroll
            for (int i = 0; i < RM; ++i)
#pragma unroll
                for (int j = 0; j < RN; ++j)
                    acc[i][j] = __builtin_amdgcn_mfma_f32_32x32x16_f16(
                        af[i], bf[j], acc[i][j], 0, 0, 0);
        }
        __syncthreads();
    }

    const int rowbL = wm * WTM;
    const int colbL = wn * WTN;

    if constexpr (OM == 1) {
        f16* Cs = (f16*)smem;
#pragma unroll
        for (int j = 0; j < RN; ++j) {
            int colL = colbL + j * 32 + l31;
            float bv = ga.bias[(int)brow0 + colL];
            int chL = colL >> 3, wi = colL & 7;
#pragma unroll
            for (int i = 0; i < RM; ++i) {
#pragma unroll
                for (int r = 0; r < 16; ++r) {
                    int rowL = rowbL + i * 32 + (r & 3) + 8 * (r >> 2) + 4 * half;
                    float v = acc[i][j][r] + bv;
                    if (SILU) v = v / (1.0f + __expf(-v));
                    Cs[rowL * BN + ((chL ^ (rowL & 15)) << 3) + wi] = (f16)v;
                }
            }
        }
        __syncthreads();
        f16* Cout = (f16*)ga.C;
#pragma unroll
        for (int pass = 0; pass < (BM * BN / 8) / 256; ++pass) {
            int s = pass * 256 + tid;
            int rowL = s >> 4;
            int ch = s & 15;
            f16x8 v = *(const f16x8*)&Cs[rowL * BN + ((ch ^ (rowL & 15)) << 3)];
            *(f16x8*)&Cout[(size_t)(arow0 + rowL) * ga.ldc + brow0 + ch * 8] = v;
        }
    } else {
        float* Cout = (float*)ga.C;
#pragma unroll
        for (int j = 0; j < RN; ++j) {
            int col = (int)brow0 + colbL + j * 32 + l31;
            float bv = ga.bias[col];
#pragma unroll
            for (int i = 0; i < RM; ++i) {
#pragma unroll
                for (int r = 0; r < 16; ++r) {
                    int row = (int)arow0 + rowbL + i * 32
                            + (r & 3) + 8 * (r >> 2) + 4 * half;
                    float v = acc[i][j][r] + bv;
                    if (SILU) v = v / (1.0f + __expf(-v));
                    Cout[(size_t)row * ga.ldc + col] = v;
                }
            }
        }
    }
}

// ---------------------------------------------------------------------------
// gemm9_k v2: 128x256x64, ONE-BARRIER-PER-PHASE schedule (m201-form),
// depth-2 counted-vmcnt, 3-buffer LDS ring (144KB).
// 512 thr = 8 waves (2M x 4N), wave tile 64x64, 16x16x32 MFMA (layout
// verified via mid_k/R5), zero-conflict swizzle (R5/R6-measured: 0).
// Phase = { 8 ds_read_b128 ; stage ; [vmcnt] ; s_barrier ; lgkmcnt(0)+
// sched_barrier ; setprio(1) 16 MFMA setprio(0) }  -- NO trailing barrier.
// 2 phases/K-tile (one per k-step), 2 barriers/tile (was 8 in R5/R6).
// Why: with reads issued immediately after the previous phase's MFMAs and
// only one sync point, waves drift: one wave's reads overlap other waves'
// MFMAs -> LDS and MFMA pipes run concurrently instead of alternating
// (R6 measured 4533 cy/tile vs ~1400 cy pipe budget: strict alternation).
// RAW gate: vmcnt(6) sits BEFORE the P2 barrier, so the barrier collects
// every wave's per-wave vmcnt guarantee before any tile t+1 read (those
// reads occur after this barrier). WAR gate: stage for t+2 targets the
// buffer last read in tile t-1; those reads drained >=1 phase (~600cy)
// before the post-issue VMEM writes (+>=300cy latency) can land.
// In-flight ledger: 6 loads/tile (B:4+A:2); stage 2 tiles ahead ->
// 12 outstanding at P2 -> vmcnt(6) completes the older tile exactly.
// ---------------------------------------------------------------------------
template<bool SILU>
__launch_bounds__(512, 2)
__global__ void gemm9_k(GSet p)
{
    int yb = blockIdx.y, gi = 0;
    if (yb >= p.yn0) { yb -= p.yn0; gi = 1; if (yb >= p.yn1) { yb -= p.yn1; gi = 2; } }
    const GArg ga = p.g[gi];

    __shared__ __align__(16) char smem[147456];   // 3 x 48KB ring

    const int tid  = threadIdx.x;
    const int lane = tid & 63, wave = tid >> 6;
    const int wm = wave >> 2, wn = wave & 3;      // 2M x 4N
    const int l15 = lane & 15, quad = lane >> 4;
    const int r7  = l15 & 7;

    const size_t arow0 = (size_t)blockIdx.x * 128;
    const size_t brow0 = (size_t)yb * 256;
    const int lda = ga.lda, K = ga.K;
    const int nt = K >> 6;                         // >= 4 for all users

    // Staging pointers (pre-swizzled source: slot s holds kseg (s&7)^(row&7))
    const f16* spA[2];
    const f16* spB[4];
#pragma unroll
    for (int q = 0; q < 2; ++q) {
        int s = q * 512 + tid;
        int urow = s >> 3;
        int kseg = (s & 7) ^ (urow & 7);
        spA[q] = ga.A + (arow0 + urow) * lda + kseg * 8;
    }
#pragma unroll
    for (int q = 0; q < 4; ++q) {
        int s = q * 512 + tid;
        int urow = s >> 3;
        int kseg = (s & 7) ^ (urow & 7);
        spB[q] = ga.W + (brow0 + urow) * K + kseg * 8;
    }

    f32x4 acc[4][4];   // [m-frag][n-frag]
#pragma unroll
    for (int i = 0; i < 4; ++i)
#pragma unroll
        for (int j = 0; j < 4; ++j)
#pragma unroll
            for (int r = 0; r < 4; ++r) acc[i][j][r] = 0.f;

    auto stageA = [&](char* buf, int q) {
        gld_lds16(spA[q], buf + (size_t)(q * 512 + tid) * 16);
        spA[q] += 64;
    };
    auto stageB = [&](char* buf, int q) {
        gld_lds16(spB[q], buf + 16384 + (size_t)(q * 512 + tid) * 16);
        spB[q] += 64;
    };

    f16x8 af[4], bf[4];
    auto readAB = [&](const char* buf, int ks) {
        int slot = (((ks << 2) | quad) ^ r7) * 16;
#pragma unroll
        for (int f = 0; f < 4; ++f) {
            int row = wm * 64 + f * 16 + l15;
            af[f] = *(const f16x8*)(buf + row * 128 + slot);
        }
#pragma unroll
        for (int f = 0; f < 4; ++f) {
            int row = wn * 64 + f * 16 + l15;
            bf[f] = *(const f16x8*)(buf + 16384 + row * 128 + slot);
        }
    };
    auto mma = [&]() {
        __builtin_amdgcn_s_setprio(1);
#pragma unroll
        for (int f = 0; f < 4; ++f)
#pragma unroll
            for (int n = 0; n < 4; ++n)
                acc[f][n] = __builtin_amdgcn_mfma_f32_16x16x32_f16(
                    af[f], bf[n], acc[f][n], 0, 0, 0);
        __builtin_amdgcn_s_setprio(0);
    };

    // Prologue: stage tiles 0 and 1 (12 loads); tile 0 ready after vmcnt(6).
    {
        char* b0 = smem;
        char* b1 = smem + 49152;
        stageB(b0, 0); stageB(b0, 1); stageB(b0, 2); stageB(b0, 3);
        stageA(b0, 0); stageA(b0, 1);
        stageB(b1, 0); stageB(b1, 1); stageB(b1, 2); stageB(b1, 3);
        stageA(b1, 0); stageA(b1, 1);
        WAITV6();
        BARX();
    }

    int bi = 0;
    for (int t = 0; t < nt; ++t) {
        char* buf = smem + bi * 49152;
        int nxi = bi + 2; if (nxi >= 3) nxi -= 3;
        char* nbuf = smem + nxi * 49152;
        const bool st = (t + 2 < nt);
        // ---- P1 (k-step 0): reads -> stage B -> barrier -> MFMA ----
        readAB(buf, 0);
        if (st) { stageB(nbuf, 0); stageB(nbuf, 1); stageB(nbuf, 2); stageB(nbuf, 3); }
        BARX(); LGK0();
        mma();
        // ---- P2 (k-step 1): reads -> stage A -> vmcnt -> barrier -> MFMA ----
        readAB(buf, 1);
        if (st) { stageA(nbuf, 0); stageA(nbuf, 1); }
        if (st) { WAITV6(); } else if (t + 2 == nt) { WAITV0(); }
        BARX(); LGK0();
        mma();
        bi += 1; if (bi >= 3) bi -= 3;
    }

    // ---- epilogue: bias + SiLU, f16 repack via LDS (ring is dead) ----
    BARX();   // ensure all waves done with LDS reads before repack overwrite
    f16* Cs = (f16*)smem;
#pragma unroll
    for (int mf = 0; mf < 4; ++mf)
#pragma unroll
        for (int nf = 0; nf < 4; ++nf) {
            int colL = wn * 64 + nf * 16 + l15;
            float bv = ga.bias[(int)brow0 + colL];
            int ch = colL >> 3, wi = colL & 7;
#pragma unroll
            for (int r = 0; r < 4; ++r) {
                int rowL = wm * 64 + mf * 16 + quad * 4 + r;
                float v = acc[mf][nf][r] + bv;
                if (SILU) v = v / (1.0f + __expf(-v));
                Cs[rowL * 256 + ((ch ^ (rowL & 31)) << 3) + wi] = (f16)v;
            }
        }
    __syncthreads();
    f16* Cout = (f16*)ga.C;
#pragma unroll
    for (int pass = 0; pass < 8; ++pass) {
        int s = pass * 512 + tid;
        int rowL = s >> 5, ch = s & 31;
        f16x8 v = *(const f16x8*)&Cs[rowL * 256 + ((ch ^ (rowL & 31)) << 3)];
        *(f16x8*)&Cout[(size_t)(arow0 + rowL) * ga.ldc + brow0 + ch * 8] = v;
    }
}

// ---------------------------------------------------------------------------
// Fused middle: e3 + a3 + b3 + Bu contraction + Koopman -> znb [B,32] f16.
// ---------------------------------------------------------------------------
__launch_bounds__(256)
__global__ void mid_k(const f16* __restrict__ cc2,
                      const f16* __restrict__ e_w3t, const float* __restrict__ e_b3,
                      const f16* __restrict__ a_w3t, const float* __restrict__ a_b3,
                      const f16* __restrict__ b_w3t, const float* __restrict__ b_b3,
                      const float* __restrict__ u,   f16* __restrict__ znb)
{
    __shared__ __align__(16) f16 As[32 * 64];
    __shared__ __align__(16) f16 Bs[128 * 64];
    __shared__ float zb[32 * 32];
    __shared__ float ab[32 * 32];
    __shared__ float bu[32 * 32];
    __shared__ float ub[32 * 16];

    const int tid  = threadIdx.x;
    const int lane = tid & 63, wave = tid >> 6;
    const int l15 = lane & 15, quad = lane >> 4;
    const int r0 = blockIdx.x * 32;

    ub[tid]       = u[r0 * 16 + tid];
    ub[tid + 256] = u[r0 * 16 + 256 + tid];

#pragma unroll 1
    for (int ph = 0; ph < 2; ++ph) {
        const f16* W    = ph ? a_w3t : e_w3t;
        const float* bs = ph ? a_b3 : e_b3;
        const int K     = ph ? 256 : 1024;
        const int co    = ph ? 1024 : 0;
        float* ob       = ph ? ab : zb;
        f32x4 acc = {0.f, 0.f, 0.f, 0.f};
        for (int k0 = 0; k0 < K; k0 += 64) {
            {
                int row = tid >> 3, sg = (tid & 7) ^ (row & 7);
                gld_lds16(cc2 + (size_t)(r0 + row) * 1536 + co + k0 + sg * 8,
                          &As[tid * 8]);
            }
            {
                int row = tid >> 3, sg = (tid & 7) ^ (row & 7);
                gld_lds16(W + (size_t)row * K + k0 + sg * 8, &Bs[tid * 8]);
            }
            __syncthreads();
#pragma unroll
            for (int kk = 0; kk < 64; kk += 32) {
                int ar = ((wave >> 1) << 4) + l15;
                int ast = ((kk >> 3) + quad) ^ (ar & 7);
                f16x8 af = *(const f16x8*)&As[(ar * 8 + ast) * 8];
                int br = ((wave & 1) << 4) + l15;
                int bst = ((kk >> 3) + quad) ^ (br & 7);
                f16x8 bf = *(const f16x8*)&Bs[(br * 8 + bst) * 8];
                acc = __builtin_amdgcn_mfma_f32_16x16x32_f16(af, bf, acc, 0, 0, 0);
            }
            __syncthreads();
        }
#pragma unroll
        for (int r = 0; r < 4; ++r) {
            int row = ((wave >> 1) << 4) + quad * 4 + r;
            int col = ((wave & 1) << 4) + l15;
            ob[row * 32 + col] = acc[r] + bs[col];
        }
    }

#pragma unroll 1
    for (int ch = 0; ch < 4; ++ch) {
        f32x4 acc[2][2];
#pragma unroll
        for (int i = 0; i < 2; ++i)
#pragma unroll
            for (int j = 0; j < 2; ++j) acc[i][j] = f32x4{0.f, 0.f, 0.f, 0.f};
        for (int k0 = 0; k0 < 256; k0 += 64) {
            {   int row = tid >> 3, sg = (tid & 7) ^ (row & 7);
                gld_lds16(cc2 + (size_t)(r0 + row) * 1536 + 1280 + k0 + sg * 8,
                          &As[tid * 8]);
            }
#pragma unroll
            for (int it = 0; it < 4; ++it) {
                int s = it * 256 + tid;
                int row = s >> 3, sg = (s & 7) ^ (row & 7);
                gld_lds16(b_w3t + (size_t)(ch * 128 + row) * 256 + k0 + sg * 8,
                          &Bs[s * 8]);
            }
            __syncthreads();
#pragma unroll
            for (int kk = 0; kk < 64; kk += 32) {
                f16x8 af[2], bf[2];
#pragma unroll
                for (int i = 0; i < 2; ++i) {
                    int ar = i * 16 + l15;
                    int st = ((kk >> 3) + quad) ^ (ar & 7);
                    af[i] = *(const f16x8*)&As[(ar * 8 + st) * 8];
                }
#pragma unroll
                for (int j = 0; j < 2; ++j) {
                    int br = wave * 32 + j * 16 + l15;
                    int st = ((kk >> 3) + quad) ^ (br & 7);
                    bf[j] = *(const f16x8*)&Bs[(br * 8 + st) * 8];
                }
#pragma unroll
                for (int i = 0; i < 2; ++i)
#pragma unroll
                    for (int j = 0; j < 2; ++j)
                        acc[i][j] = __builtin_amdgcn_mfma_f32_16x16x32_f16(
                            af[i], bf[j], acc[i][j], 0, 0, 0);
            }
            __syncthreads();
        }
#pragma unroll
        for (int j = 0; j < 2; ++j) {
            int colg = ch * 128 + wave * 32 + j * 16 + l15;
            float bv = b_b3[colg];
            int z = colg >> 4;
#pragma unroll
            for (int i = 0; i < 2; ++i) {
#pragma unroll
                for (int r = 0; r < 4; ++r) {
                    int row = i * 16 + quad * 4 + r;
                    float v = (acc[i][j][r] + bv) * ub[row * 16 + l15];
                    v += __shfl_xor(v, 8, 16);
                    v += __shfl_xor(v, 4, 16);
                    v += __shfl_xor(v, 2, 16);
                    v += __shfl_xor(v, 1, 16);
                    if (l15 == 0) bu[row * 32 + z] = v;
                }
            }
        }
    }
    __syncthreads();

#pragma unroll
    for (int t = 0; t < 4; ++t) {
        int idx = t * 256 + tid;
        int row = idx >> 5, z = idx & 31;
        int pb = idx & ~1;
        float a  = ab[pb], b = ab[pb + 1];
        float z0 = zb[pb], z1 = zb[pb + 1];
        float f  = __expf(a * DT_C);
        float c_ = __cosf(b * DT_C);
        float s_ = __sinf(b * DT_C);
        float Az = (z & 1) ? f * (s_ * z0 + c_ * z1) : f * (c_ * z0 - s_ * z1);
        float zc = (z & 1) ? z1 : z0;
        znb[(size_t)(r0 + row) * 32 + z] = (f16)(zc + DT_C * (Az + bu[idx]));
    }
}

// ---------------------------------------------------------------------------
// One-shot prep: 13 weight transposes (f32 [K,N] -> f16 [N,K]), x f32->f16,
// L1 bias concat.
// ---------------------------------------------------------------------------
struct PrepArgs {
    const float* w[13];
    f16*         wt[13];
    int          K[13];
    int          N[13];
    const float* bsrc[3];
    float*       bias1;
    const float* x;
    f16*         xb;
};

__launch_bounds__(256)
__global__ void prep_k(PrepArgs pa, int ntrans, int ncvt)
{
    int bid = blockIdx.x;
    if (bid < ntrans) {
        int i = 0, t;
        for (;; ++i) {
            t = (pa.K[i] >> 5) * (pa.N[i] >> 5);
            if (bid < t) break;
            bid -= t;
        }
        const int K = pa.K[i], N = pa.N[i];
        const int tn = N >> 5;
        const int k0 = (bid / tn) << 5, n0 = (bid % tn) << 5;
        __shared__ float tbuf[32][33];
        const int tx = threadIdx.x & 31, ty = threadIdx.x >> 5;
        const float* src = pa.w[i];
        f16* dst = pa.wt[i];
#pragma unroll
        for (int r = 0; r < 32; r += 8)
            tbuf[ty + r][tx] = src[(size_t)(k0 + ty + r) * N + n0 + tx];
        __syncthreads();
#pragma unroll
        for (int r = 0; r < 32; r += 8)
            dst[(size_t)(n0 + ty + r) * K + k0 + tx] = (f16)tbuf[tx][ty + r];
    } else if (bid < ntrans + ncvt) {
        int i = ((bid - ntrans) * 256 + threadIdx.x) * 4;
        float4 v = *(const float4*)(pa.x + i);
        f16x4 o = {(f16)v.x, (f16)v.y, (f16)v.z, (f16)v.w};
        *(f16x4*)(pa.xb + i) = o;
    } else {
        int idx = (bid - ntrans - ncvt) * 256 + (int)threadIdx.x; // 0..1535
        float v = (idx < 1024) ? pa.bsrc[0][idx]
                : (idx < 1280) ? pa.bsrc[1][idx - 1024]
                               : pa.bsrc[2][idx - 1280];
        pa.bias1[idx] = v;
    }
}

extern "C" void kernel_launch(void* const* d_in, const int* in_sizes, int n_in,
                              void* d_out, int out_size, void* d_ws, size_t ws_size,
                              hipStream_t stream)
{
    (void)in_sizes; (void)n_in; (void)out_size; (void)ws_size;
    const float* x    = (const float*)d_in[0];
    const float* u    = (const float*)d_in[1];
    const float* e_w1 = (const float*)d_in[2];  const float* e_b1 = (const float*)d_in[3];
    const float* e_w2 = (const float*)d_in[4];  const float* e_b2 = (const float*)d_in[5];
    const float* e_w3 = (const float*)d_in[6];  const float* e_b3 = (const float*)d_in[7];
    const float* d_w1 = (const float*)d_in[8];  const float* d_b1 = (const float*)d_in[9];
    const float* d_w2 = (const float*)d_in[10]; const float* d_b2 = (const float*)d_in[11];
    const float* d_w3 = (const float*)d_in[12]; const float* d_b3 = (const float*)d_in[13];
    const float* d_w4 = (const float*)d_in[14]; const float* d_b4 = (const float*)d_in[15];
    const float* a_w1 = (const float*)d_in[16]; const float* a_b1 = (const float*)d_in[17];
    const float* a_w2 = (const float*)d_in[18]; const float* a_b2 = (const float*)d_in[19];
    const float* a_w3 = (const float*)d_in[20]; const float* a_b3 = (const float*)d_in[21];
    const float* b_w1 = (const float*)d_in[22]; const float* b_b1 = (const float*)d_in[23];
    const float* b_w2 = (const float*)d_in[24]; const float* b_b2 = (const float*)d_in[25];
    const float* b_w3 = (const float*)d_in[26]; const float* b_b3 = (const float*)d_in[27];

    char* p = (char*)d_ws;
    auto alloc = [&](size_t nbytes) -> void* {
        void* r = (void*)p;
        p += (nbytes + 255) & ~(size_t)255;
        return r;
    };
    // activations
    f16*   xb   = (f16*)  alloc((size_t)B_SZ * X_D * 2);
    f16*   cc1  = (f16*)  alloc((size_t)B_SZ * 1536 * 2);  // h1e | p1a | p1b
    f16*   cc2  = (f16*)  alloc((size_t)B_SZ * 1536 * 2);  // h2e | p2a | p2b
    f16*   znb  = (f16*)  alloc((size_t)B_SZ * Z_D * 2);
    // decoder ping-pong aliases (cc1/cc2 dead by then)
    f16*   h1d  = cc1;
    f16*   h2d  = cc2;
    f16*   h3d  = cc1;
    // transposed f16 weights [N][K]
    f16*   W1t   = (f16*)alloc((size_t)1536 * X_D * 2);    // e|a|b layer-1 stacked
    float* bias1 = (float*)alloc(1536 * 4);
    f16* e_w2t = (f16*)alloc((size_t)H_D * H_D * 2);
    f16* e_w3t = (f16*)alloc((size_t)Z_D * H_D * 2);
    f16* d_w1t = (f16*)alloc((size_t)H_D * Z_D * 2);
    f16* d_w2t = (f16*)alloc((size_t)H_D * H_D * 2);
    f16* d_w3t = (f16*)alloc((size_t)H_D * H_D * 2);
    f16* d_w4t = (f16*)alloc((size_t)X_D * H_D * 2);
    f16* a_w2t = (f16*)alloc((size_t)A_D * A_D * 2);
    f16* a_w3t = (f16*)alloc((size_t)Z_D * A_D * 2);
    f16* b_w2t = (f16*)alloc((size_t)A_D * A_D * 2);
    f16* b_w3t = (f16*)alloc((size_t)(Z_D * U_D) * A_D * 2);

    // ---- prep ----
    PrepArgs pa;
    const float* ws_[13] = {e_w1, e_w2, e_w3, d_w1, d_w2, d_w3, d_w4,
                            a_w1, a_w2, a_w3, b_w1, b_w2, b_w3};
    f16* wts_[13] = {W1t, e_w2t, e_w3t, d_w1t, d_w2t, d_w3t, d_w4t,
                     W1t + (size_t)1024 * X_D, a_w2t, a_w3t,
                     W1t + (size_t)1280 * X_D, b_w2t, b_w3t};
    int Ks_[13] = {X_D, H_D, H_D, Z_D, H_D, H_D, H_D, X_D, A_D, A_D, X_D, A_D, A_D};
    int Ns_[13] = {H_D, H_D, Z_D, H_D, H_D, H_D, X_D, A_D, A_D, Z_D, A_D, A_D, Z_D*U_D};
    int ntrans = 0;
    for (int i = 0; i < 13; ++i) {
        pa.w[i] = ws_[i]; pa.wt[i] = wts_[i]; pa.K[i] = Ks_[i]; pa.N[i] = Ns_[i];
        ntrans += (Ks_[i] >> 5) * (Ns_[i] >> 5);
    }
    pa.bsrc[0] = e_b1; pa.bsrc[1] = a_b1; pa.bsrc[2] = b_b1;
    pa.bias1 = bias1; pa.x = x; pa.xb = xb;
    const int ncvt = (B_SZ * X_D) / 1024;
    prep_k<<<ntrans + ncvt + 6, 256, 0, stream>>>(pa, ntrans, ncvt);

    auto G = [](const f16* A, const f16* W, const float* bias, void* C,
                int lda, int ldc, int K) {
        GArg g; g.A = A; g.W = W; g.bias = bias; g.C = C;
        g.lda = lda; g.ldc = ldc; g.K = K; return g;
    };
    GSet s;

    // ---- fused layer-1: [B,64] @ [64,1536] -> cc1 (K=64, old kernel) ----
    s.g[0] = G(xb, W1t, bias1, cc1, X_D, 1536, X_D);
    s.yn0 = 12; s.yn1 = 0;
    gemm_k<128,128,64,2,2,true,1><<<dim3(B_SZ/128, 12), 256, 0, stream>>>(s);

    // ---- merged layer-2 via 1-barrier pipeline: e2 (4 tiles) + a2 + b2 ----
    s.g[0] = G(cc1,        e_w2t, e_b2, cc2,        1536, 1536, H_D);
    s.g[1] = G(cc1 + 1024, a_w2t, a_b2, cc2 + 1024, 1536, 1536, A_D);
    s.g[2] = G(cc1 + 1280, b_w2t, b_b2, cc2 + 1280, 1536, 1536, A_D);
    s.yn0 = 4; s.yn1 = 1;
    gemm9_k<true><<<dim3(B_SZ/128, 6), 512, 0, stream>>>(s);

    // ---- fused middle: e3+a3+b3+Bu+Koopman -> znb ----
    mid_k<<<B_SZ/32, 256, 0, stream>>>(cc2, e_w3t, e_b3, a_w3t, a_b3,
                                       b_w3t, b_b3, u, znb);

    // ---- decoder ----
    s.yn0 = 8; s.yn1 = 0;
    s.g[0] = G(znb, d_w1t, d_b1, h1d, Z_D, H_D, Z_D);
    gemm_k<128,128,32,2,2,true,1><<<dim3(B_SZ/128, 8), 256, 0, stream>>>(s);

    // d2/d3 via 1-barrier pipeline (grid 128x4 = 512 blocks, 2 uniform rounds)
    s.yn0 = 4; s.yn1 = 0;
    s.g[0] = G(h1d, d_w2t, d_b2, h2d, H_D, H_D, H_D);
    gemm9_k<true><<<dim3(B_SZ/128, 4), 512, 0, stream>>>(s);

    s.g[0] = G(h2d, d_w3t, d_b3, h3d, H_D, H_D, H_D);
    gemm9_k<true><<<dim3(B_SZ/128, 4), 512, 0, stream>>>(s);

    s.g[0] = G(h3d, d_w4t, d_b4, d_out, H_D, X_D, H_D);
    s.yn0 = 1;
    gemm_k<64,64,64,2,2,false,0><<<dim3(B_SZ/64, 1), 256, 0, stream>>>(s);
}

// Round 8
// 349.004 us; speedup vs baseline: 1.0654x; 1.0654x over previous
//
#include <hip/hip_runtime.h>
#include <cstdint>
#include <cstddef>

#define B_SZ 16384
#define X_D  64
#define U_D  16
#define Z_D  32
#define H_D  1024
#define A_D  256
#define DT_C 0.02f

typedef _Float16 f16;
typedef f16   f16x8 __attribute__((ext_vector_type(8)));
typedef f16   f16x4 __attribute__((ext_vector_type(4)));
typedef float f32x4 __attribute__((ext_vector_type(4)));
typedef float f32x16 __attribute__((ext_vector_type(16)));

#define AS1 __attribute__((address_space(1)))
#define AS3 __attribute__((address_space(3)))

__device__ __forceinline__ void gld_lds16(const void* g, void* l) {
    __builtin_amdgcn_global_load_lds((AS1 void*)(g), (AS3 void*)(l), 16, 0, 0);
}

#define BARX()  do { asm volatile("" ::: "memory"); __builtin_amdgcn_s_barrier(); \
                     asm volatile("" ::: "memory"); } while (0)
#define LGK0()  do { asm volatile("s_waitcnt lgkmcnt(0)" ::: "memory"); \
                     __builtin_amdgcn_sched_barrier(0); } while (0)
#define WAITV0() asm volatile("s_waitcnt vmcnt(0)" ::: "memory")

struct GArg {
    const f16*  A;     // [M, lda] activations (row-major subview)
    const f16*  W;     // [N, K]   transposed weights, ld == K
    const float* bias; // [N]
    void*       C;     // output
    int lda, ldc, K;
};
// Up to 3 sub-GEMMs in one launch; yn0/yn1 = #N-tiles of sub-GEMM 0/1.
struct GSet { GArg g[3]; int yn0, yn1; };

// ---------------------------------------------------------------------------
// R0 kernel (verified best for small-K launches): 128x128x64 block,
// single 32KB stage buffer (5 blocks/CU), 32x32x16 MFMA. Used for L1/d1/d4.
// ---------------------------------------------------------------------------
template<int BM,int BN,int BK,int WM,int WN,bool SILU,int OM>
__launch_bounds__(256)
__global__ void gemm_k(GSet p)
{
    static_assert(OM != 1 || BN == 128, "OM1 repack assumes BN=128");
    int yb = blockIdx.y, gi = 0;
    if (yb >= p.yn0) { yb -= p.yn0; gi = 1; if (yb >= p.yn1) { yb -= p.yn1; gi = 2; } }
    const GArg ga = p.g[gi];

    constexpr int SEGROW = BK / 8;
    constexpr int SMASK  = (SEGROW < 8 ? SEGROW : 8) - 1;
    constexpr int WTM = BM / WM, WTN = BN / WN;
    static_assert(WTM % 32 == 0 && WTN % 32 == 0, "wave tile in 32x32 units");
    constexpr int RM = WTM / 32, RN = WTN / 32;
    constexpr int KS = BK / 16;
    constexpr int ITA = (BM * SEGROW) / 256;
    constexpr int ITB = (BN * SEGROW) / 256;

    constexpr int STAGE_B = (BM + BN) * BK * 2;
    constexpr int CS_B    = (OM == 1) ? BM * BN * 2 : 0;
    constexpr int SMEM_B  = STAGE_B > CS_B ? STAGE_B : CS_B;
    __shared__ __align__(16) char smem[SMEM_B];
    f16* As = (f16*)smem;
    f16* Bs = As + BM * BK;

    const int tid  = threadIdx.x;
    const int lane = tid & 63;
    const int wave = tid >> 6;
    const int wm = wave / WN, wn = wave % WN;
    const int l31 = lane & 31, half = lane >> 5;

    const size_t arow0 = (size_t)blockIdx.x * BM;
    const size_t brow0 = (size_t)yb * BN;
    const int lda = ga.lda, K = ga.K;

    const f16* aptr[ITA];
    const f16* bptr[ITB];
#pragma unroll
    for (int it = 0; it < ITA; ++it) {
        int s = it * 256 + tid;
        int row = s / SEGROW, st = s % SEGROW;
        int sg = st ^ (row & SMASK);
        aptr[it] = ga.A + (arow0 + row) * lda + sg * 8;
    }
#pragma unroll
    for (int it = 0; it < ITB; ++it) {
        int s = it * 256 + tid;
        int row = s / SEGROW, st = s % SEGROW;
        int sg = st ^ (row & SMASK);
        bptr[it] = ga.W + (brow0 + row) * K + sg * 8;
    }

    f32x16 acc[RM][RN];
#pragma unroll
    for (int i = 0; i < RM; ++i)
#pragma unroll
        for (int j = 0; j < RN; ++j)
#pragma unroll
            for (int r = 0; r < 16; ++r) acc[i][j][r] = 0.f;

    for (int k0 = 0; k0 < K; k0 += BK) {
#pragma unroll
        for (int it = 0; it < ITA; ++it) {
            gld_lds16(aptr[it], &As[(it * 256 + tid) * 8]);
            aptr[it] += BK;
        }
#pragma unroll
        for (int it = 0; it < ITB; ++it) {
            gld_lds16(bptr[it], &Bs[(it * 256 + tid) * 8]);
            bptr[it] += BK;
        }
        __syncthreads();

#pragma unroll
        for (int ks = 0; ks < KS; ++ks) {
            f16x8 af[RM], bf[RN];
#pragma unroll
            for (int i = 0; i < RM; ++i) {
                int row = wm * WTM + i * 32 + l31;
                int st  = (ks * 2 + half) ^ (row & SMASK);
                af[i] = *(const f16x8*)&As[(row * SEGROW + st) * 8];
            }
#pragma unroll
            for (int j = 0; j < RN; ++j) {
                int row = wn * WTN + j * 32 + l31;
                int st  = (ks * 2 + half) ^ (row & SMASK);
                bf[j] = *(const f16x8*)&Bs[(row * SEGROW + st) * 8];
            }
#pragma unroll
            for (int i = 0; i < RM; ++i)
#pragma unroll
                for (int j = 0; j < RN; ++j)
                    acc[i][j] = __builtin_amdgcn_mfma_f32_32x32x16_f16(
                        af[i], bf[j], acc[i][j], 0, 0, 0);
        }
        __syncthreads();
    }

    const int rowbL = wm * WTM;
    const int colbL = wn * WTN;

    if constexpr (OM == 1) {
        f16* Cs = (f16*)smem;
#pragma unroll
        for (int j = 0; j < RN; ++j) {
            int colL = colbL + j * 32 + l31;
            float bv = ga.bias[(int)brow0 + colL];
            int chL = colL >> 3, wi = colL & 7;
#pragma unroll
            for (int i = 0; i < RM; ++i) {
#pragma unroll
                for (int r = 0; r < 16; ++r) {
                    int rowL = rowbL + i * 32 + (r & 3) + 8 * (r >> 2) + 4 * half;
                    float v = acc[i][j][r] + bv;
                    if (SILU) v = v / (1.0f + __expf(-v));
                    Cs[rowL * BN + ((chL ^ (rowL & 15)) << 3) + wi] = (f16)v;
                }
            }
        }
        __syncthreads();
        f16* Cout = (f16*)ga.C;
#pragma unroll
        for (int pass = 0; pass < (BM * BN / 8) / 256; ++pass) {
            int s = pass * 256 + tid;
            int rowL = s >> 4;
            int ch = s & 15;
            f16x8 v = *(const f16x8*)&Cs[rowL * BN + ((ch ^ (rowL & 15)) << 3)];
            *(f16x8*)&Cout[(size_t)(arow0 + rowL) * ga.ldc + brow0 + ch * 8] = v;
        }
    } else {
        float* Cout = (float*)ga.C;
#pragma unroll
        for (int j = 0; j < RN; ++j) {
            int col = (int)brow0 + colbL + j * 32 + l31;
            float bv = ga.bias[col];
#pragma unroll
            for (int i = 0; i < RM; ++i) {
#pragma unroll
                for (int r = 0; r < 16; ++r) {
                    int row = (int)arow0 + rowbL + i * 32
                            + (r & 3) + 8 * (r >> 2) + 4 * half;
                    float v = acc[i][j][r] + bv;
                    if (SILU) v = v / (1.0f + __expf(-v));
                    Cout[(size_t)row * ga.ldc + col] = v;
                }
            }
        }
    }
}

// ---------------------------------------------------------------------------
// gemm10_k: faithful m201-template port. 256x256x64, 512 thr = 8 waves
// (2M x 4N), wave tile 128x64, 16x16x32 MFMA (fragment math identical to
// verified mid_k). LDS 128KB = 2 buffers x {A 256x64 (32K) | B 256x64 (32K)},
// 128-B rows, slot-XOR swizzle (R5/R7-measured: 0 bank conflicts),
// pre-swizzled global staging source.
// Per K-tile: 4 C-QUADRANT phases (mh,nh) over full K=64:
//   P1(0,0): readA(mh0) 8 + readB(nh0) 4 + stage 4xB   } phase body:
//   P2(0,1): readB(nh1) 4            + stage 4xA       } reads; stage;
//   P3(1,1): readA(mh1) 8                              } BAR; lgkm0;
//   P4(1,0): readB(nh0) 4 + [vmcnt(0)]                 } setprio+16 MFMA; BAR
// The vmcnt(0) at P4 waits on loads whose YOUNGEST was issued 2 phases
// (~1300cy) earlier (> HBM latency) -> lands on completed loads, ~free.
// Geometry gives 16 MFMA per barrier-section and ~40 FLOP per LDS byte
// (R5-R7's 64x64 wave tile: 32.8) -- the m201 combination of T2 swizzle +
// quadrant phases + covered waits that R3..R7 each had only pieces of.
// Hazards: all tile t-1 ds_reads complete before t-1 P4's trailing barrier
// (every wave lgkm-gates its reads before its MFMAs), so tile-t stage
// writes (issued after that barrier, +>=300cy flight) cannot race; staged
// data is waited+barriered before its first read. Barriers wave-uniform.
// ---------------------------------------------------------------------------
template<bool SILU>
__launch_bounds__(512, 2)
__global__ void gemm10_k(GSet p)
{
    int yb = blockIdx.y, gi = 0;
    if (yb >= p.yn0) { yb -= p.yn0; gi = 1; if (yb >= p.yn1) { yb -= p.yn1; gi = 2; } }
    const GArg ga = p.g[gi];

    __shared__ __align__(16) char smem[131072];   // 2 x {A 32K | B 32K}

    const int tid  = threadIdx.x;
    const int lane = tid & 63, wave = tid >> 6;
    const int wm = wave >> 2, wn = wave & 3;      // 2M x 4N
    const int l15 = lane & 15, quad = lane >> 4;

    const size_t arow0 = (size_t)blockIdx.x * 256;
    const size_t brow0 = (size_t)yb * 256;
    const int lda = ga.lda, K = ga.K;
    const int nt = K >> 6;

    // Staging: unit q covers rows [q*64, q*64+64); slot s holds logical
    // kseg (s&7)^(row&7) -> pre-swizzled global source (verified pair).
    const f16* spA[4];
    const f16* spB[4];
#pragma unroll
    for (int q = 0; q < 4; ++q) {
        int s = q * 512 + tid;
        int row = s >> 3;
        int kseg = (s & 7) ^ (row & 7);
        spA[q] = ga.A + (arow0 + row) * lda + kseg * 8;
        spB[q] = ga.W + (brow0 + row) * K + kseg * 8;
    }

    f32x4 acc[8][4];   // [m-frag 0..7][n-frag 0..3]
#pragma unroll
    for (int i = 0; i < 8; ++i)
#pragma unroll
        for (int j = 0; j < 4; ++j)
#pragma unroll
            for (int r = 0; r < 4; ++r) acc[i][j][r] = 0.f;

    auto stageA = [&](char* buf, int q) {
        gld_lds16(spA[q], buf + (size_t)(q * 512 + tid) * 16);
        spA[q] += 64;
    };
    auto stageB = [&](char* buf, int q) {
        gld_lds16(spB[q], buf + 32768 + (size_t)(q * 512 + tid) * 16);
        spB[q] += 64;
    };

    f16x8 af[4][2], bf[2][2];
    auto readA = [&](const char* buf, int mh) {
#pragma unroll
        for (int i = 0; i < 4; ++i) {
            int ar = wm * 128 + mh * 64 + i * 16 + l15;
#pragma unroll
            for (int ks = 0; ks < 2; ++ks) {
                int st = (ks * 4 + quad) ^ (ar & 7);
                af[i][ks] = *(const f16x8*)(buf + ar * 128 + st * 16);
            }
        }
    };
    auto readB = [&](const char* buf, int nh) {
#pragma unroll
        for (int j = 0; j < 2; ++j) {
            int br = wn * 64 + nh * 32 + j * 16 + l15;
#pragma unroll
            for (int ks = 0; ks < 2; ++ks) {
                int st = (ks * 4 + quad) ^ (br & 7);
                bf[j][ks] = *(const f16x8*)(buf + 32768 + br * 128 + st * 16);
            }
        }
    };
    auto mma = [&](int mh, int nh) {
        __builtin_amdgcn_s_setprio(1);
#pragma unroll
        for (int ks = 0; ks < 2; ++ks)
#pragma unroll
            for (int i = 0; i < 4; ++i)
#pragma unroll
                for (int j = 0; j < 2; ++j)
                    acc[mh * 4 + i][nh * 2 + j] =
                        __builtin_amdgcn_mfma_f32_16x16x32_f16(
                            af[i][ks], bf[j][ks], acc[mh * 4 + i][nh * 2 + j],
                            0, 0, 0);
        __builtin_amdgcn_s_setprio(0);
    };

    // Prologue: stage tile 0 into buf0, drain (cold latency paid once).
    {
        char* b0 = smem;
        stageB(b0, 0); stageB(b0, 1); stageB(b0, 2); stageB(b0, 3);
        stageA(b0, 0); stageA(b0, 1); stageA(b0, 2); stageA(b0, 3);
        WAITV0();
        BARX();
    }

    for (int t = 0; t < nt; ++t) {
        char* buf  = smem + (size_t)(t & 1) * 65536;
        char* nbuf = smem + (size_t)((t & 1) ^ 1) * 65536;
        const bool st = (t + 1 < nt);
        // P1 (mh0, nh0): 12 reads + 4 B-stages
        readA(buf, 0); readB(buf, 0);
        if (st) { stageB(nbuf, 0); stageB(nbuf, 1); stageB(nbuf, 2); stageB(nbuf, 3); }
        BARX(); LGK0(); mma(0, 0); BARX();
        // P2 (mh0, nh1): 4 reads + 4 A-stages (all 8 loads in flight by here)
        readB(buf, 1);
        if (st) { stageA(nbuf, 0); stageA(nbuf, 1); stageA(nbuf, 2); stageA(nbuf, 3); }
        BARX(); LGK0(); mma(0, 1); BARX();
        // P3 (mh1, nh1): 8 reads
        readA(buf, 1);
        BARX(); LGK0(); mma(1, 1); BARX();
        // P4 (mh1, nh0): 4 reads; wait covers loads issued >=2 phases ago
        readB(buf, 0);
        if (st) WAITV0();
        BARX(); LGK0(); mma(1, 0); BARX();
    }

    // ---- epilogue: bias + SiLU, f16 repack via LDS (buffers dead) ----
    f16* Cs = (f16*)smem;
#pragma unroll
    for (int mf = 0; mf < 8; ++mf)
#pragma unroll
        for (int nf = 0; nf < 4; ++nf) {
            int colL = wn * 64 + (nf >> 1) * 32 + (nf & 1) * 16 + l15;
            float bv = ga.bias[(int)brow0 + colL];
            int ch = colL >> 3, wi = colL & 7;
#pragma unroll
            for (int r = 0; r < 4; ++r) {
                int rowL = wm * 128 + (mf >> 2) * 64 + (mf & 3) * 16 + quad * 4 + r;
                float v = acc[mf][nf][r] + bv;
                if (SILU) v = v / (1.0f + __expf(-v));
                Cs[rowL * 256 + ((ch ^ (rowL & 31)) << 3) + wi] = (f16)v;
            }
        }
    __syncthreads();
    f16* Cout = (f16*)ga.C;
#pragma unroll
    for (int pass = 0; pass < 16; ++pass) {
        int s = pass * 512 + tid;
        int rowL = s >> 5, ch = s & 31;
        f16x8 v = *(const f16x8*)&Cs[rowL * 256 + ((ch ^ (rowL & 31)) << 3)];
        *(f16x8*)&Cout[(size_t)(arow0 + rowL) * ga.ldc + brow0 + ch * 8] = v;
    }
}

// ---------------------------------------------------------------------------
// Fused middle: e3 + a3 + b3 + Bu contraction + Koopman -> znb [B,32] f16.
// ---------------------------------------------------------------------------
__launch_bounds__(256)
__global__ void mid_k(const f16* __restrict__ cc2,
                      const f16* __restrict__ e_w3t, const float* __restrict__ e_b3,
                      const f16* __restrict__ a_w3t, const float* __restrict__ a_b3,
                      const f16* __restrict__ b_w3t, const float* __restrict__ b_b3,
                      const float* __restrict__ u,   f16* __restrict__ znb)
{
    __shared__ __align__(16) f16 As[32 * 64];
    __shared__ __align__(16) f16 Bs[128 * 64];
    __shared__ float zb[32 * 32];
    __shared__ float ab[32 * 32];
    __shared__ float bu[32 * 32];
    __shared__ float ub[32 * 16];

    const int tid  = threadIdx.x;
    const int lane = tid & 63, wave = tid >> 6;
    const int l15 = lane & 15, quad = lane >> 4;
    const int r0 = blockIdx.x * 32;

    ub[tid]       = u[r0 * 16 + tid];
    ub[tid + 256] = u[r0 * 16 + 256 + tid];

#pragma unroll 1
    for (int ph = 0; ph < 2; ++ph) {
        const f16* W    = ph ? a_w3t : e_w3t;
        const float* bs = ph ? a_b3 : e_b3;
        const int K     = ph ? 256 : 1024;
        const int co    = ph ? 1024 : 0;
        float* ob       = ph ? ab : zb;
        f32x4 acc = {0.f, 0.f, 0.f, 0.f};
        for (int k0 = 0; k0 < K; k0 += 64) {
            {
                int row = tid >> 3, sg = (tid & 7) ^ (row & 7);
                gld_lds16(cc2 + (size_t)(r0 + row) * 1536 + co + k0 + sg * 8,
                          &As[tid * 8]);
            }
            {
                int row = tid >> 3, sg = (tid & 7) ^ (row & 7);
                gld_lds16(W + (size_t)row * K + k0 + sg * 8, &Bs[tid * 8]);
            }
            __syncthreads();
#pragma unroll
            for (int kk = 0; kk < 64; kk += 32) {
                int ar = ((wave >> 1) << 4) + l15;
                int ast = ((kk >> 3) + quad) ^ (ar & 7);
                f16x8 af = *(const f16x8*)&As[(ar * 8 + ast) * 8];
                int br = ((wave & 1) << 4) + l15;
                int bst = ((kk >> 3) + quad) ^ (br & 7);
                f16x8 bf = *(const f16x8*)&Bs[(br * 8 + bst) * 8];
                acc = __builtin_amdgcn_mfma_f32_16x16x32_f16(af, bf, acc, 0, 0, 0);
            }
            __syncthreads();
        }
#pragma unroll
        for (int r = 0; r < 4; ++r) {
            int row = ((wave >> 1) << 4) + quad * 4 + r;
            int col = ((wave & 1) << 4) + l15;
            ob[row * 32 + col] = acc[r] + bs[col];
        }
    }

#pragma unroll 1
    for (int ch = 0; ch < 4; ++ch) {
        f32x4 acc[2][2];
#pragma unroll
        for (int i = 0; i < 2; ++i)
#pragma unroll
            for (int j = 0; j < 2; ++j) acc[i][j] = f32x4{0.f, 0.f, 0.f, 0.f};
        for (int k0 = 0; k0 < 256; k0 += 64) {
            {   int row = tid >> 3, sg = (tid & 7) ^ (row & 7);
                gld_lds16(cc2 + (size_t)(r0 + row) * 1536 + 1280 + k0 + sg * 8,
                          &As[tid * 8]);
            }
#pragma unroll
            for (int it = 0; it < 4; ++it) {
                int s = it * 256 + tid;
                int row = s >> 3, sg = (s & 7) ^ (row & 7);
                gld_lds16(b_w3t + (size_t)(ch * 128 + row) * 256 + k0 + sg * 8,
                          &Bs[s * 8]);
            }
            __syncthreads();
#pragma unroll
            for (int kk = 0; kk < 64; kk += 32) {
                f16x8 af[2], bf[2];
#pragma unroll
                for (int i = 0; i < 2; ++i) {
                    int ar = i * 16 + l15;
                    int st = ((kk >> 3) + quad) ^ (ar & 7);
                    af[i] = *(const f16x8*)&As[(ar * 8 + st) * 8];
                }
#pragma unroll
                for (int j = 0; j < 2; ++j) {
                    int br = wave * 32 + j * 16 + l15;
                    int st = ((kk >> 3) + quad) ^ (br & 7);
                    bf[j] = *(const f16x8*)&Bs[(br * 8 + st) * 8];
                }
#pragma unroll
                for (int i = 0; i < 2; ++i)
#pragma unroll
                    for (int j = 0; j < 2; ++j)
                        acc[i][j] = __builtin_amdgcn_mfma_f32_16x16x32_f16(
                            af[i], bf[j], acc[i][j], 0, 0, 0);
            }
            __syncthreads();
        }
#pragma unroll
        for (int j = 0; j < 2; ++j) {
            int colg = ch * 128 + wave * 32 + j * 16 + l15;
            float bv = b_b3[colg];
            int z = colg >> 4;
#pragma unroll
            for (int i = 0; i < 2; ++i) {
#pragma unroll
                for (int r = 0; r < 4; ++r) {
                    int row = i * 16 + quad * 4 + r;
                    float v = (acc[i][j][r] + bv) * ub[row * 16 + l15];
                    v += __shfl_xor(v, 8, 16);
                    v += __shfl_xor(v, 4, 16);
                    v += __shfl_xor(v, 2, 16);
                    v += __shfl_xor(v, 1, 16);
                    if (l15 == 0) bu[row * 32 + z] = v;
                }
            }
        }
    }
    __syncthreads();

#pragma unroll
    for (int t = 0; t < 4; ++t) {
        int idx = t * 256 + tid;
        int row = idx >> 5, z = idx & 31;
        int pb = idx & ~1;
        float a  = ab[pb], b = ab[pb + 1];
        float z0 = zb[pb], z1 = zb[pb + 1];
        float f  = __expf(a * DT_C);
        float c_ = __cosf(b * DT_C);
        float s_ = __sinf(b * DT_C);
        float Az = (z & 1) ? f * (s_ * z0 + c_ * z1) : f * (c_ * z0 - s_ * z1);
        float zc = (z & 1) ? z1 : z0;
        znb[(size_t)(r0 + row) * 32 + z] = (f16)(zc + DT_C * (Az + bu[idx]));
    }
}

// ---------------------------------------------------------------------------
// One-shot prep: 13 weight transposes (f32 [K,N] -> f16 [N,K]), x f32->f16,
// L1 bias concat.
// ---------------------------------------------------------------------------
struct PrepArgs {
    const float* w[13];
    f16*         wt[13];
    int          K[13];
    int          N[13];
    const float* bsrc[3];
    float*       bias1;
    const float* x;
    f16*         xb;
};

__launch_bounds__(256)
__global__ void prep_k(PrepArgs pa, int ntrans, int ncvt)
{
    int bid = blockIdx.x;
    if (bid < ntrans) {
        int i = 0, t;
        for (;; ++i) {
            t = (pa.K[i] >> 5) * (pa.N[i] >> 5);
            if (bid < t) break;
            bid -= t;
        }
        const int K = pa.K[i], N = pa.N[i];
        const int tn = N >> 5;
        const int k0 = (bid / tn) << 5, n0 = (bid % tn) << 5;
        __shared__ float tbuf[32][33];
        const int tx = threadIdx.x & 31, ty = threadIdx.x >> 5;
        const float* src = pa.w[i];
        f16* dst = pa.wt[i];
#pragma unroll
        for (int r = 0; r < 32; r += 8)
            tbuf[ty + r][tx] = src[(size_t)(k0 + ty + r) * N + n0 + tx];
        __syncthreads();
#pragma unroll
        for (int r = 0; r < 32; r += 8)
            dst[(size_t)(n0 + ty + r) * K + k0 + tx] = (f16)tbuf[tx][ty + r];
    } else if (bid < ntrans + ncvt) {
        int i = ((bid - ntrans) * 256 + threadIdx.x) * 4;
        float4 v = *(const float4*)(pa.x + i);
        f16x4 o = {(f16)v.x, (f16)v.y, (f16)v.z, (f16)v.w};
        *(f16x4*)(pa.xb + i) = o;
    } else {
        int idx = (bid - ntrans - ncvt) * 256 + (int)threadIdx.x; // 0..1535
        float v = (idx < 1024) ? pa.bsrc[0][idx]
                : (idx < 1280) ? pa.bsrc[1][idx - 1024]
                               : pa.bsrc[2][idx - 1280];
        pa.bias1[idx] = v;
    }
}

extern "C" void kernel_launch(void* const* d_in, const int* in_sizes, int n_in,
                              void* d_out, int out_size, void* d_ws, size_t ws_size,
                              hipStream_t stream)
{
    (void)in_sizes; (void)n_in; (void)out_size; (void)ws_size;
    const float* x    = (const float*)d_in[0];
    const float* u    = (const float*)d_in[1];
    const float* e_w1 = (const float*)d_in[2];  const float* e_b1 = (const float*)d_in[3];
    const float* e_w2 = (const float*)d_in[4];  const float* e_b2 = (const float*)d_in[5];
    const float* e_w3 = (const float*)d_in[6];  const float* e_b3 = (const float*)d_in[7];
    const float* d_w1 = (const float*)d_in[8];  const float* d_b1 = (const float*)d_in[9];
    const float* d_w2 = (const float*)d_in[10]; const float* d_b2 = (const float*)d_in[11];
    const float* d_w3 = (const float*)d_in[12]; const float* d_b3 = (const float*)d_in[13];
    const float* d_w4 = (const float*)d_in[14]; const float* d_b4 = (const float*)d_in[15];
    const float* a_w1 = (const float*)d_in[16]; const float* a_b1 = (const float*)d_in[17];
    const float* a_w2 = (const float*)d_in[18]; const float* a_b2 = (const float*)d_in[19];
    const float* a_w3 = (const float*)d_in[20]; const float* a_b3 = (const float*)d_in[21];
    const float* b_w1 = (const float*)d_in[22]; const float* b_b1 = (const float*)d_in[23];
    const float* b_w2 = (const float*)d_in[24]; const float* b_b2 = (const float*)d_in[25];
    const float* b_w3 = (const float*)d_in[26]; const float* b_b3 = (const float*)d_in[27];

    char* p = (char*)d_ws;
    auto alloc = [&](size_t nbytes) -> void* {
        void* r = (void*)p;
        p += (nbytes + 255) & ~(size_t)255;
        return r;
    };
    // activations
    f16*   xb   = (f16*)  alloc((size_t)B_SZ * X_D * 2);
    f16*   cc1  = (f16*)  alloc((size_t)B_SZ * 1536 * 2);  // h1e | p1a | p1b
    f16*   cc2  = (f16*)  alloc((size_t)B_SZ * 1536 * 2);  // h2e | p2a | p2b
    f16*   znb  = (f16*)  alloc((size_t)B_SZ * Z_D * 2);
    // decoder ping-pong aliases (cc1/cc2 dead by then)
    f16*   h1d  = cc1;
    f16*   h2d  = cc2;
    f16*   h3d  = cc1;
    // transposed f16 weights [N][K]
    f16*   W1t   = (f16*)alloc((size_t)1536 * X_D * 2);    // e|a|b layer-1 stacked
    float* bias1 = (float*)alloc(1536 * 4);
    f16* e_w2t = (f16*)alloc((size_t)H_D * H_D * 2);
    f16* e_w3t = (f16*)alloc((size_t)Z_D * H_D * 2);
    f16* d_w1t = (f16*)alloc((size_t)H_D * Z_D * 2);
    f16* d_w2t = (f16*)alloc((size_t)H_D * H_D * 2);
    f16* d_w3t = (f16*)alloc((size_t)H_D * H_D * 2);
    f16* d_w4t = (f16*)alloc((size_t)X_D * H_D * 2);
    f16* a_w2t = (f16*)alloc((size_t)A_D * A_D * 2);
    f16* a_w3t = (f16*)alloc((size_t)Z_D * A_D * 2);
    f16* b_w2t = (f16*)alloc((size_t)A_D * A_D * 2);
    f16* b_w3t = (f16*)alloc((size_t)(Z_D * U_D) * A_D * 2);

    // ---- prep ----
    PrepArgs pa;
    const float* ws_[13] = {e_w1, e_w2, e_w3, d_w1, d_w2, d_w3, d_w4,
                            a_w1, a_w2, a_w3, b_w1, b_w2, b_w3};
    f16* wts_[13] = {W1t, e_w2t, e_w3t, d_w1t, d_w2t, d_w3t, d_w4t,
                     W1t + (size_t)1024 * X_D, a_w2t, a_w3t,
                     W1t + (size_t)1280 * X_D, b_w2t, b_w3t};
    int Ks_[13] = {X_D, H_D, H_D, Z_D, H_D, H_D, H_D, X_D, A_D, A_D, X_D, A_D, A_D};
    int Ns_[13] = {H_D, H_D, Z_D, H_D, H_D, H_D, X_D, A_D, A_D, Z_D, A_D, A_D, Z_D*U_D};
    int ntrans = 0;
    for (int i = 0; i < 13; ++i) {
        pa.w[i] = ws_[i]; pa.wt[i] = wts_[i]; pa.K[i] = Ks_[i]; pa.N[i] = Ns_[i];
        ntrans += (Ks_[i] >> 5) * (Ns_[i] >> 5);
    }
    pa.bsrc[0] = e_b1; pa.bsrc[1] = a_b1; pa.bsrc[2] = b_b1;
    pa.bias1 = bias1; pa.x = x; pa.xb = xb;
    const int ncvt = (B_SZ * X_D) / 1024;
    prep_k<<<ntrans + ncvt + 6, 256, 0, stream>>>(pa, ntrans, ncvt);

    auto G = [](const f16* A, const f16* W, const float* bias, void* C,
                int lda, int ldc, int K) {
        GArg g; g.A = A; g.W = W; g.bias = bias; g.C = C;
        g.lda = lda; g.ldc = ldc; g.K = K; return g;
    };
    GSet s;

    // ---- fused layer-1: [B,64] @ [64,1536] -> cc1 (K=64, old kernel) ----
    s.g[0] = G(xb, W1t, bias1, cc1, X_D, 1536, X_D);
    s.yn0 = 12; s.yn1 = 0;
    gemm_k<128,128,64,2,2,true,1><<<dim3(B_SZ/128, 12), 256, 0, stream>>>(s);

    // ---- merged layer-2 via m201-port: e2 (4 tiles) + a2 (1) + b2 (1) ----
    s.g[0] = G(cc1,        e_w2t, e_b2, cc2,        1536, 1536, H_D);
    s.g[1] = G(cc1 + 1024, a_w2t, a_b2, cc2 + 1024, 1536, 1536, A_D);
    s.g[2] = G(cc1 + 1280, b_w2t, b_b2, cc2 + 1280, 1536, 1536, A_D);
    s.yn0 = 4; s.yn1 = 1;
    gemm10_k<true><<<dim3(B_SZ/256, 6), 512, 0, stream>>>(s);

    // ---- fused middle: e3+a3+b3+Bu+Koopman -> znb ----
    mid_k<<<B_SZ/32, 256, 0, stream>>>(cc2, e_w3t, e_b3, a_w3t, a_b3,
                                       b_w3t, b_b3, u, znb);

    // ---- decoder ----
    s.yn0 = 8; s.yn1 = 0;
    s.g[0] = G(znb, d_w1t, d_b1, h1d, Z_D, H_D, Z_D);
    gemm_k<128,128,32,2,2,true,1><<<dim3(B_SZ/128, 8), 256, 0, stream>>>(s);

    // d2/d3 via m201-port (grid 64x4 = 256 blocks = exactly 1/CU, 1 round)
    s.yn0 = 4; s.yn1 = 0;
    s.g[0] = G(h1d, d_w2t, d_b2, h2d, H_D, H_D, H_D);
    gemm10_k<true><<<dim3(B_SZ/256, 4), 512, 0, stream>>>(s);

    s.g[0] = G(h2d, d_w3t, d_b3, h3d, H_D, H_D, H_D);
    gemm10_k<true><<<dim3(B_SZ/256, 4), 512, 0, stream>>>(s);

    s.g[0] = G(h3d, d_w4t, d_b4, d_out, H_D, X_D, H_D);
    s.yn0 = 1;
    gemm_k<64,64,64,2,2,false,0><<<dim3(B_SZ/64, 1), 256, 0, stream>>>(s);
}